// Round 6
// baseline (190.821 us; speedup 1.0000x reference)
//
#include <hip/hip_runtime.h>
#include <hip/hip_bf16.h>

typedef __bf16 b16;
typedef __bf16 b16x8 __attribute__((ext_vector_type(8)));
typedef float  f32x4 __attribute__((ext_vector_type(4)));

#define B_   64
#define N_   196
#define C_   768
#define H_   12
#define HD_  64
#define TOK  (B_*N_)      // 12544
#define SCALE 0.125f

// async global->LDS, 16B per lane, wave-uniform LDS base
__device__ __forceinline__ void gl_lds16(const void* g, void* l){
  __builtin_amdgcn_global_load_lds((const __attribute__((address_space(1))) void*)g,
                                   (__attribute__((address_space(3))) void*)l, 16, 0, 0);
}

// ---------------------------------------------------------------- transpose+cvt
__global__ __launch_bounds__(256) void k_transpose_cvt(const float* __restrict__ in,
                                                       b16* __restrict__ out, int R, int C){
  __shared__ b16 tile[32][33];
  int tx = threadIdx.x, ty = threadIdx.y;
  int bx = blockIdx.x, by = blockIdx.y;
  int c = bx*32 + tx;
  #pragma unroll
  for (int i = 0; i < 32; i += 8){
    int r = by*32 + ty + i;
    tile[ty+i][tx] = (b16)in[(long)r*C + c];
  }
  __syncthreads();
  int rr = by*32 + tx;
  #pragma unroll
  for (int i = 0; i < 32; i += 8){
    int cc = bx*32 + ty + i;
    out[(long)cc*R + rr] = tile[tx][ty+i];
  }
}

// ---------------------------------------------------------------- x f32 -> bf16
__global__ __launch_bounds__(256) void k_cvt(const float* __restrict__ in, b16* __restrict__ out){
  long i = ((long)blockIdx.x*256 + threadIdx.x)*8;
  const float4* s = (const float4*)(in + i);
  float4 f0 = s[0], f1 = s[1];
  b16x8 v; v[0]=(b16)f0.x; v[1]=(b16)f0.y; v[2]=(b16)f0.z; v[3]=(b16)f0.w;
           v[4]=(b16)f1.x; v[5]=(b16)f1.y; v[6]=(b16)f1.z; v[7]=(b16)f1.w;
  *(b16x8*)(out + i) = v;
}

// ---------------------------------------------------------------- K = k^T k, ksum (4 blocks)
__global__ __launch_bounds__(256) void k_kprep(const float* __restrict__ k_ext,
                                               float* __restrict__ Kmat, float* __restrict__ ksum){
  __shared__ float ks[N_][HD_];
  int tid = threadIdx.x, blk = blockIdx.x;       // blk 0..3
  for (int i = tid; i < N_*HD_; i += 256) ks[i/HD_][i%HD_] = k_ext[i];
  __syncthreads();
  int i = tid >> 2;
  int j0 = blk*16 + (tid & 3)*4;
  float a0=0.f, a1=0.f, a2=0.f, a3=0.f;
  for (int p = 0; p < N_; ++p){
    float ki = ks[p][i];
    float4 kv = *(const float4*)&ks[p][j0];
    a0 += ki*kv.x; a1 += ki*kv.y; a2 += ki*kv.z; a3 += ki*kv.w;
  }
  Kmat[i*64+j0+0]=a0; Kmat[i*64+j0+1]=a1; Kmat[i*64+j0+2]=a2; Kmat[i*64+j0+3]=a3;
  if (blk == 0 && tid < 64){
    float s = 0.f;
    for (int p = 0; p < N_; ++p) s += ks[p][tid];
    ksum[tid] = s;
  }
}

// ---------------------------------------------------------------- tiled bf16 MFMA GEMM
// 256x128 tile, BK=64, 8 waves (2M x 4N), 3 rotating LDS buffers (144 KiB),
// ONE barrier + ONE counted vmcnt(6) per K-tile, phase-interleaved stage/ds_read/MFMA,
// setprio around MFMA clusters. Pre-swizzled source + swizzled read (both-sides, verified).
// MODE0: scatter q/v bf16 [b,h,n,d] + fused BN stats; MODE1: f32 out + bias
template<int MODE>
__global__ __launch_bounds__(512, 2) void k_gemm(const b16* __restrict__ A,
                                                 const b16* __restrict__ BT,
                                                 b16* __restrict__ qout, b16* __restrict__ vout,
                                                 float* __restrict__ fout, const float* __restrict__ bias,
                                                 const float* __restrict__ ksum, float* __restrict__ stats){
  const int NT  = (MODE == 0) ? 12 : 6;
  const int NWG = 49*NT;
  extern __shared__ char smc[];          // 3 * (32768 A + 16384 B) = 147456 B
  // bijective XCD swizzle (m204)
  int orig = blockIdx.x;
  int q8 = NWG >> 3, r8 = NWG & 7;
  int xcd = orig & 7, loc = orig >> 3;
  int bid = (xcd < r8 ? xcd*(q8+1) : r8*(q8+1) + (xcd-r8)*q8) + loc;
  int rt = bid / NT, ct = bid % NT;
  int brow = rt*256, bcol = ct*128;

  int tid = threadIdx.x, lane = tid & 63, w = tid >> 6;
  int wr = w >> 2, wc = w & 3;

  // staging: each gl_lds covers 8 rows x 64 cols; lane l -> row +(l>>3), slot l&7.
  // source pre-swizzle: global group g = (l&7) ^ (l>>3 & 7); read-side XOR matches.
  int lrow8 = lane >> 3;
  int g8 = (lane & 7) ^ lrow8;
  const b16* gA = A  + (long)(brow + w*8 + lrow8)*768 + g8*8;
  const b16* gB = BT + (long)(bcol + w*8 + lrow8)*768 + g8*8;

#define STAGE_A01(bb, t) do{ long ko = (long)(t)*64; \
    gl_lds16(gA + ko,           smc + (bb) + (0*8+w)*1024); \
    gl_lds16(gA + 64*768 + ko,  smc + (bb) + (1*8+w)*1024); } while(0)
#define STAGE_A23(bb, t) do{ long ko = (long)(t)*64; \
    gl_lds16(gA + 128*768 + ko, smc + (bb) + (2*8+w)*1024); \
    gl_lds16(gA + 192*768 + ko, smc + (bb) + (3*8+w)*1024); } while(0)
#define STAGE_B(bb, t) do{ long ko = (long)(t)*64; \
    gl_lds16(gB + ko,           smc + (bb) + 32768 + (0*8+w)*1024); \
    gl_lds16(gB + 64*768 + ko,  smc + (bb) + 32768 + (1*8+w)*1024); } while(0)

  // ds_read fragment addressing: row&7 == lane&7 for all fragments (row = X*16 + (lane&15))
#define LDA(bb, mm, kh) (*(const b16x8*)(smc + (bb) + (wr*128 + (mm)*16 + (lane&15))*128 \
                          + ((((kh)*4 + (lane>>4)) ^ (lane&7))<<4)))
#define LDB(bb, nn, kh) (*(const b16x8*)(smc + (bb) + 32768 + (wc*32 + (nn)*16 + (lane&15))*128 \
                          + ((((kh)*4 + (lane>>4)) ^ (lane&7))<<4)))

  f32x4 acc[8][2];
  #pragma unroll
  for (int m = 0; m < 8; ++m){ acc[m][0] = (f32x4){0.f,0.f,0.f,0.f}; acc[m][1] = (f32x4){0.f,0.f,0.f,0.f}; }

  // prologue: tiles 0,1 in flight (12 loads)
  STAGE_A01(0, 0); STAGE_A23(0, 0); STAGE_B(0, 0);
  STAGE_A01(49152, 1); STAGE_A23(49152, 1); STAGE_B(49152, 1);

  #pragma unroll 1
  for (int kt = 0; kt < 12; ++kt){
    int bb = (kt % 3) * 49152;
    int sb = ((kt+2) % 3) * 49152;
    bool do_stage = (kt < 10);
    // --- K-tile gate: counted vmcnt + single barrier ---
    if (kt < 11) asm volatile("s_waitcnt vmcnt(6)" ::: "memory");
    else         asm volatile("s_waitcnt vmcnt(0)" ::: "memory");
    __builtin_amdgcn_s_barrier();
    asm volatile("" ::: "memory");

    b16x8 af[8], bf0, bf1;
    // ---- K-half 0: reads, stage A01, MFMA n=0; stage A23, MFMA n=1 ----
    #pragma unroll
    for (int m = 0; m < 8; ++m) af[m] = LDA(bb, m, 0);
    bf0 = LDB(bb, 0, 0);
    bf1 = LDB(bb, 1, 0);
    if (do_stage) STAGE_A01(sb, kt+2);
    asm volatile("s_waitcnt lgkmcnt(0)" ::: "memory");
    __builtin_amdgcn_sched_barrier(0);
    __builtin_amdgcn_s_setprio(1);
    #pragma unroll
    for (int m = 0; m < 8; ++m)
      acc[m][0] = __builtin_amdgcn_mfma_f32_16x16x32_bf16(af[m], bf0, acc[m][0], 0, 0, 0);
    __builtin_amdgcn_s_setprio(0);
    __builtin_amdgcn_sched_barrier(0);
    if (do_stage) STAGE_A23(sb, kt+2);
    __builtin_amdgcn_sched_barrier(0);
    __builtin_amdgcn_s_setprio(1);
    #pragma unroll
    for (int m = 0; m < 8; ++m)
      acc[m][1] = __builtin_amdgcn_mfma_f32_16x16x32_bf16(af[m], bf1, acc[m][1], 0, 0, 0);
    __builtin_amdgcn_s_setprio(0);
    __builtin_amdgcn_sched_barrier(0);
    // ---- K-half 1 ----
    #pragma unroll
    for (int m = 0; m < 8; ++m) af[m] = LDA(bb, m, 1);
    bf0 = LDB(bb, 0, 1);
    bf1 = LDB(bb, 1, 1);
    if (do_stage) STAGE_B(sb, kt+2);
    asm volatile("s_waitcnt lgkmcnt(0)" ::: "memory");
    __builtin_amdgcn_sched_barrier(0);
    __builtin_amdgcn_s_setprio(1);
    #pragma unroll
    for (int m = 0; m < 8; ++m)
      acc[m][0] = __builtin_amdgcn_mfma_f32_16x16x32_bf16(af[m], bf0, acc[m][0], 0, 0, 0);
    __builtin_amdgcn_s_setprio(0);
    __builtin_amdgcn_sched_barrier(0);
    __builtin_amdgcn_s_setprio(1);
    #pragma unroll
    for (int m = 0; m < 8; ++m)
      acc[m][1] = __builtin_amdgcn_mfma_f32_16x16x32_bf16(af[m], bf1, acc[m][1], 0, 0, 0);
    __builtin_amdgcn_s_setprio(0);
    __builtin_amdgcn_sched_barrier(0);
  }
#undef STAGE_A01
#undef STAGE_A23
#undef STAGE_B
#undef LDA
#undef LDB

  if constexpr (MODE == 0){
    #pragma unroll
    for (int m = 0; m < 8; ++m){
      #pragma unroll
      for (int n = 0; n < 2; ++n){
        int col = bcol + wc*32 + n*16 + (lane & 15);
        int two = (col >= 768) ? 1 : 0;
        int hc = col - two*768;
        int hh = hc >> 6, d = hc & 63;
        b16* dst = two ? vout : qout;
        #pragma unroll
        for (int j = 0; j < 4; ++j){
          int r2 = brow + wr*128 + m*16 + ((lane>>4)<<2) + j;
          int bq = r2 / 196;
          int nn2 = r2 - bq*196;
          dst[((bq*12 + hh)*196 + nn2)*64 + d] = (b16)acc[m][n][j];
        }
      }
    }
    // fused BN stats: per wave all 32 cols belong to ONE head
    {
      bool isV = (bcol >= 768);
      float a_acc = 0.f, b_acc = 0.f;
      #pragma unroll
      for (int n = 0; n < 2; ++n){
        int d = (wc & 1)*32 + n*16 + (lane & 15);   // col within head
        float s = 0.f, s2 = 0.f;
        #pragma unroll
        for (int m = 0; m < 8; ++m)
          #pragma unroll
          for (int j = 0; j < 4; ++j){
            float v = acc[m][n][j];
            s += v; s2 += v*v;
          }
        if (isV){ a_acc += s; b_acc += s2; }
        else      a_acc += s * ksum[d];
      }
      #pragma unroll
      for (int off = 1; off < 64; off <<= 1){
        a_acc += __shfl_xor(a_acc, off, 64);
        b_acc += __shfl_xor(b_acc, off, 64);
      }
      if (lane == 0){
        if (isV){
          int hv = 2*(ct - 6) + (wc >> 1);
          atomicAdd(&stats[24 + hv], a_acc);
          atomicAdd(&stats[36 + hv], b_acc);
        } else {
          int hq = 2*ct + (wc >> 1);
          atomicAdd(&stats[hq], a_acc);
        }
      }
    }
  } else {
    #pragma unroll
    for (int m = 0; m < 8; ++m){
      #pragma unroll
      for (int n = 0; n < 2; ++n){
        int col = bcol + wc*32 + n*16 + (lane & 15);
        float bv = bias[col];
        #pragma unroll
        for (int j = 0; j < 4; ++j){
          int r2 = brow + wr*128 + m*16 + ((lane>>4)<<2) + j;
          fout[(long)r2*768 + col] = acc[m][n][j] + bv;
        }
      }
    }
  }
}

// ---------------------------------------------------------------- per-head Gram G = sum_t q q^T (MFMA)
__global__ __launch_bounds__(256) void k_gram(const b16* __restrict__ qb, float* __restrict__ G){
  __shared__ b16 qT[64*232];          // [d][t] stride 232
  int tid = threadIdx.x, lane = tid & 63, w = tid >> 6;
  int h = blockIdx.x % 12, bg = blockIdx.x / 12;   // bg 0..31
  f32x4 acc[4];
  #pragma unroll
  for (int n = 0; n < 4; ++n) acc[n] = (f32x4){0.f,0.f,0.f,0.f};
  #pragma unroll 1
  for (int r = 0; r < 2; ++r){
    int b = bg*2 + r;
    const b16* src = qb + ((long)(b*12 + h))*196*64;
    int d = lane;
    for (int p0 = w*8; p0 < 224; p0 += 32){
      b16x8 w8;
      #pragma unroll
      for (int j = 0; j < 8; ++j){
        int p = p0 + j;
        w8[j] = (p < 196) ? src[p*64 + d] : (b16)0.f;
      }
      *(b16x8*)(qT + d*232 + p0) = w8;
    }
    __syncthreads();
    #pragma unroll
    for (int ks = 0; ks < 7; ++ks){
      int t0 = ks*32;
      b16x8 af = *(const b16x8*)(qT + (16*w + (lane&15))*232 + t0 + ((lane>>4)<<3));
      #pragma unroll
      for (int n = 0; n < 4; ++n){
        b16x8 bf = *(const b16x8*)(qT + (16*n + (lane&15))*232 + t0 + ((lane>>4)<<3));
        acc[n] = __builtin_amdgcn_mfma_f32_16x16x32_bf16(af, bf, acc[n], 0, 0, 0);
      }
    }
    __syncthreads();
  }
  float* Gh = G + h*4096;
  #pragma unroll
  for (int n = 0; n < 4; ++n)
    #pragma unroll
    for (int j = 0; j < 4; ++j){
      int i  = 16*w + ((lane>>4)<<2) + j;
      int jj = 16*n + (lane&15);
      atomicAdd(&Gh[i*64 + jj], acc[n][j]);
    }
}

// ---------------------------------------------------------------- S2 = <G,K>, finalize coefs
__global__ __launch_bounds__(256) void k_sfin(const float* __restrict__ G, const float* __restrict__ Kmat,
                                              const float* __restrict__ stats, const float* __restrict__ gamma,
                                              const float* __restrict__ beta, float* __restrict__ coef){
  int h = blockIdx.x, tid = threadIdx.x;
  const float* Gh = G + h*4096;
  float s = 0.f;
  #pragma unroll
  for (int k = 0; k < 16; ++k) s += Gh[tid + k*256]*Kmat[tid + k*256];
  #pragma unroll
  for (int off = 1; off < 64; off <<= 1) s += __shfl_xor(s, off, 64);
  __shared__ float red[4];
  if ((tid & 63) == 0) red[tid>>6] = s;
  __syncthreads();
  if (tid == 0){
    float S2 = red[0]+red[1]+red[2]+red[3];
    const float cntS = 2458624.f, cntV = 802816.f;
    float S1 = stats[h], VS = stats[24+h], VS2 = stats[36+h];
    float ms = S1/cntS;
    float vars = S2/cntS - ms*ms;
    float alpha = gamma[h]*SCALE*rsqrtf(vars + 1e-5f);
    float mv = VS/cntV;
    float varv = VS2/cntV - mv*mv;
    float a = gamma[h]*rsqrtf(varv + 1e-5f);
    coef[h*4+0] = alpha;
    coef[h*4+1] = a;
    coef[h*4+2] = beta[h] - a*mv;
  }
}

// ---------------------------------------------------------------- fused attention per (b,h)
__global__ __launch_bounds__(256, 2) void k_attn(const b16* __restrict__ qb, const b16* __restrict__ vb,
                                                 const float* __restrict__ k_ext,
                                                 const float* __restrict__ attn_bias,
                                                 const float* __restrict__ coef,
                                                 b16* __restrict__ Ob){
  __shared__ b16 ksh[196*64];
  __shared__ b16 vsh[64*216];
  __shared__ b16 psh[4][16*200];
  __shared__ float bsh[196];

  int tid = threadIdx.x, lane = tid & 63, wid = tid >> 6;
  int bh = blockIdx.x;
  int h = bh % 12, b = bh / 12;
  const b16* qt = qb + (long)bh*N_*64;
  const b16* vt = vb + (long)bh*N_*64;
  float alpha = coef[h*4+0], av = coef[h*4+1], cv = coef[h*4+2];

  for (int c = tid; c < 196*8; c += 256){
    int p = c >> 3, g = c & 7;
    const float4* src = (const float4*)(k_ext + p*64 + g*8);
    float4 f0 = src[0], f1 = src[1];
    b16x8 v; v[0]=(b16)f0.x; v[1]=(b16)f0.y; v[2]=(b16)f0.z; v[3]=(b16)f0.w;
             v[4]=(b16)f1.x; v[5]=(b16)f1.y; v[6]=(b16)f1.z; v[7]=(b16)f1.w;
    *(b16x8*)((char*)ksh + p*128 + ((g ^ (p&7))<<4)) = v;
  }
  for (int p = tid; p < 196; p += 256) bsh[p] = attn_bias[p]*SCALE;
  {
    int d = tid & 63;
    for (int p0 = (tid>>6)*8; p0 < 196; p0 += 32){
      b16x8 w;
      #pragma unroll
      for (int j = 0; j < 8; ++j){
        int p = p0 + j;
        w[j] = (p < 196) ? vt[p*64 + d] : (b16)0.f;
      }
      *(b16x8*)((char*)vsh + d*432 + p0*2) = w;
    }
  }
  __syncthreads();

  for (int rt = wid; rt < 13; rt += 4){
    int n0 = rt*16;
    int qrow = n0 + (lane & 15); if (qrow > 195) qrow = 195;
    b16x8 a0 = *(const b16x8*)((const char*)qt + qrow*128 +      ((lane>>4)<<4));
    b16x8 a1 = *(const b16x8*)((const char*)qt + qrow*128 + 64 + ((lane>>4)<<4));

    f32x4 sc[13];
    #pragma unroll
    for (int ct = 0; ct < 13; ++ct){
      int p = ct*16 + (lane & 15); int pc = p > 195 ? 195 : p;
      b16x8 b0 = *(const b16x8*)((const char*)ksh + pc*128 + ((( (lane>>4))   ^ (pc&7))<<4));
      b16x8 b1 = *(const b16x8*)((const char*)ksh + pc*128 + (((4+(lane>>4))  ^ (pc&7))<<4));
      f32x4 z = {0.f,0.f,0.f,0.f};
      z = __builtin_amdgcn_mfma_f32_16x16x32_bf16(a0, b0, z, 0, 0, 0);
      z = __builtin_amdgcn_mfma_f32_16x16x32_bf16(a1, b1, z, 0, 0, 0);
      sc[ct] = z;
    }
    int pcol = lane & 15;
    float mx[4] = {-1e30f,-1e30f,-1e30f,-1e30f};
    #pragma unroll
    for (int ct = 0; ct < 13; ++ct){
      int p = ct*16 + pcol;
      bool valid = (p < 196);
      float badd = valid ? bsh[p < 196 ? p : 0] : 0.f;
      #pragma unroll
      for (int j = 0; j < 4; ++j){
        float lv = valid ? (sc[ct][j]*alpha + badd) : -1e30f;
        sc[ct][j] = lv;
        mx[j] = fmaxf(mx[j], lv);
      }
    }
    #pragma unroll
    for (int off = 1; off < 16; off <<= 1)
      #pragma unroll
      for (int j = 0; j < 4; ++j) mx[j] = fmaxf(mx[j], __shfl_xor(mx[j], off, 64));
    float sm[4] = {0.f,0.f,0.f,0.f};
    #pragma unroll
    for (int ct = 0; ct < 13; ++ct)
      #pragma unroll
      for (int j = 0; j < 4; ++j){
        float e = __expf(sc[ct][j] - mx[j]);
        sc[ct][j] = e; sm[j] += e;
      }
    #pragma unroll
    for (int off = 1; off < 16; off <<= 1)
      #pragma unroll
      for (int j = 0; j < 4; ++j) sm[j] += __shfl_xor(sm[j], off, 64);
    float rs[4];
    #pragma unroll
    for (int j = 0; j < 4; ++j) rs[j] = 1.f/sm[j];

    b16* pw = psh[wid];
    #pragma unroll
    for (int ct = 0; ct < 12; ++ct){
      int p = ct*16 + pcol;
      #pragma unroll
      for (int j = 0; j < 4; ++j){
        int r = ((lane>>4)<<2) + j;
        pw[r*200 + p] = (b16)(sc[ct][j]*rs[j]);
      }
    }
    float pt12[4];
    #pragma unroll
    for (int j = 0; j < 4; ++j) pt12[j] = sc[12][j]*rs[j];

    __asm__ volatile("s_waitcnt lgkmcnt(0)" ::: "memory");
    __builtin_amdgcn_sched_barrier(0);

    f32x4 o[4];
    #pragma unroll
    for (int dt = 0; dt < 4; ++dt) o[dt] = (f32x4){0.f,0.f,0.f,0.f};
    #pragma unroll
    for (int pt = 0; pt < 6; ++pt){
      b16x8 pa = *(const b16x8*)((const char*)pw + (lane&15)*400 + pt*64 + ((lane>>4)<<4));
      #pragma unroll
      for (int dt = 0; dt < 4; ++dt){
        b16x8 vf = *(const b16x8*)((const char*)vsh + (dt*16 + (lane&15))*432 + pt*64 + ((lane>>4)<<4));
        o[dt] = __builtin_amdgcn_mfma_f32_16x16x32_bf16(pa, vf, o[dt], 0, 0, 0);
      }
    }
    #pragma unroll
    for (int e = 0; e < 4; ++e){
      float pe[4];
      #pragma unroll
      for (int j = 0; j < 4; ++j) pe[j] = __shfl(pt12[j], (lane & 48) + e, 64);
      #pragma unroll
      for (int dt = 0; dt < 4; ++dt){
        b16 vv = *((const b16*)((const char*)vsh + (dt*16 + (lane&15))*432 + (192+e)*2));
        float vvf = (float)vv;
        #pragma unroll
        for (int j = 0; j < 4; ++j) o[dt][j] += pe[j]*vvf;
      }
    }
    #pragma unroll
    for (int dt = 0; dt < 4; ++dt)
      #pragma unroll
      for (int j = 0; j < 4; ++j){
        int n = n0 + ((lane>>4)<<2) + j;
        if (n < 196){
          long idx = ((long)(b*196 + n))*768 + h*64 + dt*16 + (lane&15);
          Ob[idx] = (b16)(av*o[dt][j] + cv);
        }
      }
  }
}

// ---------------------------------------------------------------- launch
extern "C" void kernel_launch(void* const* d_in, const int* in_sizes, int n_in,
                              void* d_out, int out_size, void* d_ws, size_t ws_size,
                              hipStream_t stream){
  const float* x         = (const float*)d_in[0];
  const float* W_qv      = (const float*)d_in[1];
  const float* k_ext     = (const float*)d_in[2];
  const float* attn_bias = (const float*)d_in[3];
  const float* bn_gamma  = (const float*)d_in[4];
  const float* bn_beta   = (const float*)d_in[5];
  const float* W_proj    = (const float*)d_in[6];
  const float* b_proj    = (const float*)d_in[7];
  float* out = (float*)d_out;

  char* ws = (char*)d_ws;
  const long SZ = 19267584;              // 9,633,792 bf16
  b16*   q_buf   = (b16*)(ws);
  b16*   v_buf   = (b16*)(ws + SZ);
  b16*   O_buf   = (b16*)(ws + 2*SZ);    // doubles as x_bf16 before k_attn
  b16*   x_bf16  = (b16*)(ws + 2*SZ);
  b16*   W_qvT   = (b16*)(ws + 3*SZ);
  b16*   W_projT = (b16*)(ws + 3*SZ + 2359296);
  float* Kmat    = (float*)(ws + 3*SZ + 3538944);   // 4096 f32
  float* ksum    = Kmat + 4096;                     // 64 f32
  float* stats   = ksum + 64;                       // 48 f32
  float* coef    = stats + 48;                      // 48 f32
  float* Ggram   = coef + 48;                       // 12*4096 f32

  hipMemsetAsync(stats, 0, 48*sizeof(float), stream);
  hipMemsetAsync(Ggram, 0, 12*4096*sizeof(float), stream);

  dim3 tb(32, 8);
  k_transpose_cvt<<<dim3(1536/32, 768/32), tb, 0, stream>>>(W_qv,   W_qvT,   768, 1536);
  k_transpose_cvt<<<dim3(768/32,  768/32), tb, 0, stream>>>(W_proj, W_projT, 768, 768);
  k_cvt<<<4704, 256, 0, stream>>>(x, x_bf16);
  k_kprep<<<4, 256, 0, stream>>>(k_ext, Kmat, ksum);
  k_gemm<0><<<49*12, 512, 147456, stream>>>(x_bf16, W_qvT, q_buf, v_buf, nullptr, nullptr, ksum, stats);
  k_gram<<<384, 256, 0, stream>>>(q_buf, Ggram);
  k_sfin<<<12, 256, 0, stream>>>(Ggram, Kmat, stats, bn_gamma, bn_beta, coef);
  k_attn<<<768, 256, 0, stream>>>(q_buf, v_buf, k_ext, attn_bias, coef, O_buf);
  k_gemm<1><<<49*6, 512, 147456, stream>>>(O_buf, W_projT, nullptr, nullptr, out, b_proj, nullptr, nullptr);
}